// Round 3
// baseline (368.701 us; speedup 1.0000x reference)
//
#include <hip/hip_runtime.h>
#include <math.h>

#define HW   112
#define HW2  (112 * 112)
#define NIMG 64
#define CIN  128
#define NKG  4            // split-K groups over input channels
#define ICG  (CIN / NKG)  // 32 ic per group

__device__ __forceinline__ float gelu_exact(float v) {
    return 0.5f * v * (1.0f + erff(v * 0.70710678118654752f));
}

// ---------------------------------------------------------------------------
// K1a: partial[kg][n][oc][h][w] = sum over ic in group kg of conv3x3(x, w1)
// grid (7 h-tiles, 64 n, NKG), block (14, 16); thread: 8-wide strip, both oc.
// Branch-free inner loop: boundary rows read a zero-filled row in ws,
// w-edges use clamped loads * {0,1} mask -> compiler can software-pipeline.
// ---------------------------------------------------------------------------
__global__ __launch_bounds__(224, 4) void k1_partial(
    const float* __restrict__ x, const float* __restrict__ w1,
    const float* __restrict__ zrow, float* __restrict__ part) {
    const int n  = blockIdx.y;
    const int kg = blockIdx.z;
    const int h  = blockIdx.x * 16 + threadIdx.y;
    const int w0 = threadIdx.x * 8;
    const int icb = kg * ICG;

    const bool vtop = (h > 0);
    const bool vbot = (h < HW - 1);
    const float lmask = (w0 > 0) ? 1.0f : 0.0f;
    const float rmask = (w0 + 8 < HW) ? 1.0f : 0.0f;
    const int wl = (w0 > 0) ? w0 - 1 : 0;
    const int wr = (w0 + 8 < HW) ? w0 + 8 : HW - 1;

    float acc0[8] = {0.f, 0.f, 0.f, 0.f, 0.f, 0.f, 0.f, 0.f};
    float acc1[8] = {0.f, 0.f, 0.f, 0.f, 0.f, 0.f, 0.f, 0.f};

    const float* xn = x + ((size_t)n * CIN + icb) * HW2;
    const size_t off1 = (size_t)h * HW;

#pragma unroll 2
    for (int ic = 0; ic < ICG; ++ic) {
        const float* xc = xn + (size_t)ic * HW2;
        const float* r0 = vtop ? (xc + off1 - HW) : zrow;
        const float* r1 = xc + off1;
        const float* r2 = vbot ? (xc + off1 + HW) : zrow;
        const float* wa = w1 + (icb + ic) * 9;          // oc = 0
        const float* wb = w1 + (CIN + icb + ic) * 9;    // oc = 1
        const float* rows[3] = {r0, r1, r2};
#pragma unroll
        for (int dh = 0; dh < 3; ++dh) {
            const float* rp = rows[dh];
            const float4 A = *reinterpret_cast<const float4*>(rp + w0);
            const float4 B = *reinterpret_cast<const float4*>(rp + w0 + 4);
            const float L = rp[wl] * lmask;
            const float R = rp[wr] * rmask;
            const float v0 = L,   v1 = A.x, v2 = A.y, v3 = A.z, v4 = A.w;
            const float v5 = B.x, v6 = B.y, v7 = B.z, v8 = B.w, v9 = R;
            const float a0 = wa[dh * 3], a1 = wa[dh * 3 + 1], a2 = wa[dh * 3 + 2];
            const float c0 = wb[dh * 3], c1 = wb[dh * 3 + 1], c2 = wb[dh * 3 + 2];
            acc0[0] += a0 * v0 + a1 * v1 + a2 * v2;
            acc0[1] += a0 * v1 + a1 * v2 + a2 * v3;
            acc0[2] += a0 * v2 + a1 * v3 + a2 * v4;
            acc0[3] += a0 * v3 + a1 * v4 + a2 * v5;
            acc0[4] += a0 * v4 + a1 * v5 + a2 * v6;
            acc0[5] += a0 * v5 + a1 * v6 + a2 * v7;
            acc0[6] += a0 * v6 + a1 * v7 + a2 * v8;
            acc0[7] += a0 * v7 + a1 * v8 + a2 * v9;
            acc1[0] += c0 * v0 + c1 * v1 + c2 * v2;
            acc1[1] += c0 * v1 + c1 * v2 + c2 * v3;
            acc1[2] += c0 * v2 + c1 * v3 + c2 * v4;
            acc1[3] += c0 * v3 + c1 * v4 + c2 * v5;
            acc1[4] += c0 * v4 + c1 * v5 + c2 * v6;
            acc1[5] += c0 * v5 + c1 * v6 + c2 * v7;
            acc1[6] += c0 * v6 + c1 * v7 + c2 * v8;
            acc1[7] += c0 * v7 + c1 * v8 + c2 * v9;
        }
    }

    const size_t base = ((size_t)kg * NIMG + n) * 2;
    float* p0 = part + (base + 0) * HW2 + off1 + w0;
    float* p1 = part + (base + 1) * HW2 + off1 + w0;
    *reinterpret_cast<float4*>(p0)     = make_float4(acc0[0], acc0[1], acc0[2], acc0[3]);
    *reinterpret_cast<float4*>(p0 + 4) = make_float4(acc0[4], acc0[5], acc0[6], acc0[7]);
    *reinterpret_cast<float4*>(p1)     = make_float4(acc1[0], acc1[1], acc1[2], acc1[3]);
    *reinterpret_cast<float4*>(p1 + 4) = make_float4(acc1[4], acc1[5], acc1[6], acc1[7]);
}

// K1b: g = gelu(sum_kg partial + bias)
__global__ __launch_bounds__(256) void k1b_reduce_gelu(
    const float* __restrict__ part, const float* __restrict__ b1,
    float* __restrict__ g, int total4) {
    int idx = blockIdx.x * blockDim.x + threadIdx.x;
    if (idx >= total4) return;
    const size_t stride = (size_t)NIMG * 2 * HW2;  // floats per group
    const size_t e = (size_t)idx * 4;
    const int oc = (int)((e / HW2) & 1);
    float4 s = *reinterpret_cast<const float4*>(part + e);
#pragma unroll
    for (int kg = 1; kg < NKG; ++kg) {
        const float4 p = *reinterpret_cast<const float4*>(part + kg * stride + e);
        s.x += p.x; s.y += p.y; s.z += p.z; s.w += p.w;
    }
    const float bb = b1[oc];
    float4 o;
    o.x = gelu_exact(s.x + bb);
    o.y = gelu_exact(s.y + bb);
    o.z = gelu_exact(s.z + bb);
    o.w = gelu_exact(s.w + bb);
    *reinterpret_cast<float4*>(g + e) = o;
}

// ---------------------------------------------------------------------------
// Fallback monolithic K1 (used only if ws is too small for split-K buffers)
// ---------------------------------------------------------------------------
__global__ __launch_bounds__(448) void k1_conv1_gelu(
    const float* __restrict__ x, const float* __restrict__ w1,
    const float* __restrict__ b1, float* __restrict__ g) {
    const int n  = blockIdx.y;
    const int h  = blockIdx.x * 16 + threadIdx.y;
    const int w0 = threadIdx.x * 4;

    float acc0[4], acc1[4];
    const float bb0 = b1[0], bb1 = b1[1];
#pragma unroll
    for (int j = 0; j < 4; ++j) { acc0[j] = bb0; acc1[j] = bb1; }

    const float* xn = x + (size_t)n * CIN * HW2;

#pragma unroll 4
    for (int ic = 0; ic < CIN; ++ic) {
        const float* xc = xn + (size_t)ic * HW2;
        const float* wa = w1 + ic * 9;
        const float* wb = w1 + (CIN + ic) * 9;
#pragma unroll
        for (int dh = -1; dh <= 1; ++dh) {
            const int hh = h + dh;
            if (hh < 0 || hh >= HW) continue;
            const float* xr = xc + hh * HW;
            const float4 c4  = *reinterpret_cast<const float4*>(xr + w0);
            const float left  = (w0 > 0)      ? xr[w0 - 1] : 0.0f;
            const float right = (w0 + 4 < HW) ? xr[w0 + 4] : 0.0f;
            const float v0 = left, v1 = c4.x, v2 = c4.y, v3 = c4.z, v4 = c4.w, v5 = right;
            const int r = (dh + 1) * 3;
            const float a0 = wa[r], a1 = wa[r + 1], a2 = wa[r + 2];
            const float c0 = wb[r], c1 = wb[r + 1], c2 = wb[r + 2];
            acc0[0] += a0 * v0 + a1 * v1 + a2 * v2;
            acc0[1] += a0 * v1 + a1 * v2 + a2 * v3;
            acc0[2] += a0 * v2 + a1 * v3 + a2 * v4;
            acc0[3] += a0 * v3 + a1 * v4 + a2 * v5;
            acc1[0] += c0 * v0 + c1 * v1 + c2 * v2;
            acc1[1] += c0 * v1 + c1 * v2 + c2 * v3;
            acc1[2] += c0 * v2 + c1 * v3 + c2 * v4;
            acc1[3] += c0 * v3 + c1 * v4 + c2 * v5;
        }
    }

    float4 o0, o1;
    o0.x = gelu_exact(acc0[0]); o0.y = gelu_exact(acc0[1]);
    o0.z = gelu_exact(acc0[2]); o0.w = gelu_exact(acc0[3]);
    o1.x = gelu_exact(acc1[0]); o1.y = gelu_exact(acc1[1]);
    o1.z = gelu_exact(acc1[2]); o1.w = gelu_exact(acc1[3]);
    float* g0 = g + (size_t)(n * 2 + 0) * HW2 + h * HW + w0;
    float* g1 = g + (size_t)(n * 2 + 1) * HW2 + h * HW + w0;
    *reinterpret_cast<float4*>(g0) = o0;
    *reinterpret_cast<float4*>(g1) = o1;
}

// K2: s0 = softmax(gelu(conv3x3(g, w2) + b2))[ch 0]  (softmax2 == sigmoid)
__global__ __launch_bounds__(448) void k2_conv2_softmax(
    const float* __restrict__ g, const float* __restrict__ w2,
    const float* __restrict__ b2, float* __restrict__ s0) {
    const int n  = blockIdx.y;
    const int h  = blockIdx.x * 16 + threadIdx.y;
    const int w0 = threadIdx.x * 4;

    float accA[4], accB[4];
    const float bb0 = b2[0], bb1 = b2[1];
#pragma unroll
    for (int j = 0; j < 4; ++j) { accA[j] = bb0; accB[j] = bb1; }

#pragma unroll
    for (int c = 0; c < 2; ++c) {
        const float* gc = g + (size_t)(n * 2 + c) * HW2;
        const float* wa = w2 + c * 9;
        const float* wb = w2 + (2 + c) * 9;
#pragma unroll
        for (int dh = -1; dh <= 1; ++dh) {
            const int hh = h + dh;
            if (hh < 0 || hh >= HW) continue;
            const float* gr = gc + hh * HW;
            const float4 c4  = *reinterpret_cast<const float4*>(gr + w0);
            const float left  = (w0 > 0)      ? gr[w0 - 1] : 0.0f;
            const float right = (w0 + 4 < HW) ? gr[w0 + 4] : 0.0f;
            const float v0 = left, v1 = c4.x, v2 = c4.y, v3 = c4.z, v4 = c4.w, v5 = right;
            const int r = (dh + 1) * 3;
            const float a0 = wa[r], a1 = wa[r + 1], a2 = wa[r + 2];
            const float c0 = wb[r], c1 = wb[r + 1], c2 = wb[r + 2];
            accA[0] += a0 * v0 + a1 * v1 + a2 * v2;
            accA[1] += a0 * v1 + a1 * v2 + a2 * v3;
            accA[2] += a0 * v2 + a1 * v3 + a2 * v4;
            accA[3] += a0 * v3 + a1 * v4 + a2 * v5;
            accB[0] += c0 * v0 + c1 * v1 + c2 * v2;
            accB[1] += c0 * v1 + c1 * v2 + c2 * v3;
            accB[2] += c0 * v2 + c1 * v3 + c2 * v4;
            accB[3] += c0 * v3 + c1 * v4 + c2 * v5;
        }
    }

    float4 o;
    o.x = 1.0f / (1.0f + expf(gelu_exact(accB[0]) - gelu_exact(accA[0])));
    o.y = 1.0f / (1.0f + expf(gelu_exact(accB[1]) - gelu_exact(accA[1])));
    o.z = 1.0f / (1.0f + expf(gelu_exact(accB[2]) - gelu_exact(accA[2])));
    o.w = 1.0f / (1.0f + expf(gelu_exact(accB[3]) - gelu_exact(accA[3])));
    *reinterpret_cast<float4*>(s0 + (size_t)n * HW2 + h * HW + w0) = o;
}

// K3: out[b][c][t][h][w] = s0*x1 + (1-s0)*x2
__global__ __launch_bounds__(256) void k3_blend(
    const float* __restrict__ x, const float* __restrict__ s0,
    float* __restrict__ out, int total4) {
    int idx = blockIdx.x * blockDim.x + threadIdx.x;
    if (idx >= total4) return;
    const int W4 = HW / 4;
    int w4  = idx % W4;
    int tmp = idx / W4;
    int h   = tmp % HW; tmp /= HW;
    int t   = tmp % 16; tmp /= 16;
    int c   = tmp % 64;
    int b   = tmp / 64;
    const int n = b * 16 + t;

    const size_t px = (size_t)h * HW + w4 * 4;
    const float4 x1 = *reinterpret_cast<const float4*>(x + (size_t)(n * CIN + c)      * HW2 + px);
    const float4 x2 = *reinterpret_cast<const float4*>(x + (size_t)(n * CIN + c + 64) * HW2 + px);
    const float4 s  = *reinterpret_cast<const float4*>(s0 + (size_t)n * HW2 + px);

    float4 o;
    o.x = s.x * x1.x + (1.0f - s.x) * x2.x;
    o.y = s.y * x1.y + (1.0f - s.y) * x2.y;
    o.z = s.z * x1.z + (1.0f - s.z) * x2.z;
    o.w = s.w * x1.w + (1.0f - s.w) * x2.w;
    *reinterpret_cast<float4*>(out + (size_t)idx * 4) = o;
}

extern "C" void kernel_launch(void* const* d_in, const int* in_sizes, int n_in,
                              void* d_out, int out_size, void* d_ws, size_t ws_size,
                              hipStream_t stream) {
    const float* x  = (const float*)d_in[0];
    const float* w1 = (const float*)d_in[1];
    const float* b1 = (const float*)d_in[2];
    const float* w2 = (const float*)d_in[3];
    const float* b2 = (const float*)d_in[4];
    float* out = (float*)d_out;

    const size_t partF = (size_t)NKG * NIMG * 2 * HW2;  // 6.42M floats = 25.7 MB
    const size_t gF    = (size_t)NIMG * 2 * HW2;        // 1.6M  floats =  6.4 MB
    const size_t s0F   = (size_t)NIMG * HW2;            // 0.8M  floats =  3.2 MB
    const size_t zF    = HW;                            // 112-float zero row
    const size_t need  = (partF + gF + s0F + zF) * sizeof(float);

    dim3 grd(7, NIMG);

    float *g, *s0;
    if (ws_size >= need) {
        float* part = (float*)d_ws;
        g  = part + partF;
        s0 = g + gF;
        float* zrow = s0 + s0F;
        hipMemsetAsync(zrow, 0, zF * sizeof(float), stream);
        dim3 blkp(14, 16);
        dim3 grdp(7, NIMG, NKG);
        k1_partial<<<grdp, blkp, 0, stream>>>(x, w1, zrow, part);
        const int total4g = (int)(gF / 4);
        k1b_reduce_gelu<<<(total4g + 255) / 256, 256, 0, stream>>>(part, b1, g, total4g);
    } else {
        g  = (float*)d_ws;
        s0 = g + gF;
        dim3 blk(28, 16);
        k1_conv1_gelu<<<grd, blk, 0, stream>>>(x, w1, b1, g);
    }

    dim3 blk2(28, 16);
    k2_conv2_softmax<<<grd, blk2, 0, stream>>>(g, w2, b2, s0);

    const int total4 = 4 * 64 * 16 * HW * (HW / 4);
    k3_blend<<<(total4 + 255) / 256, 256, 0, stream>>>(x, s0, out, total4);
}

// Round 5
// 209.710 us; speedup vs baseline: 1.7581x; 1.7581x over previous
//
#include <hip/hip_runtime.h>
#include <math.h>
#include <stdint.h>

#define HW    112
#define HW2   (112 * 112)
#define NIMG  64
#define CIN   128
#define NKG   4            // split-K groups over input channels
#define ICG   (CIN / NKG)  // 32 ic per group
#define TILEF (18 * HW)    // 2016 staged floats per buffer
#define TILEP 2032         // padded buffer stride (16B-aligned, covers masked read)

__device__ __forceinline__ float gelu_exact(float v) {
    return 0.5f * v * (1.0f + erff(v * 0.70710678118654752f));
}

// ---------------------------------------------------------------------------
// K1a: partial[kg][n][oc][h][w] = sum over ic-group of conv3x3(x, w1)
// Block 256 threads; per block: one (n, 16-row tile, kg). Double-buffered LDS
// staging via global_load_lds(16B); compute overlaps next-channel prefetch.
// Thread (tx,ty) = (tid&15, tid>>4): 7 consecutive px in row h0+ty, both oc.
// ---------------------------------------------------------------------------
__global__ __launch_bounds__(256) void k1_partial(
    const float* __restrict__ x, const float* __restrict__ w1,
    float* __restrict__ part) {
    __shared__ __align__(16) float tile[2][TILEP];

    const int tid = threadIdx.x;
    const int bx  = blockIdx.x;   // 0..6 h-tiles
    const int n   = blockIdx.y;
    const int kg  = blockIdx.z;
    const int h0  = bx * 16;
    const int icb = kg * ICG;

    const int tx   = tid & 15;
    const int ty   = tid >> 4;
    const int col0 = tx * 7;

    // zero border rows once (never overwritten by staging)
    if (bx == 0 && tid < HW) { tile[0][tid] = 0.f; tile[1][tid] = 0.f; }
    if (bx == 6 && tid < HW) { tile[0][17 * HW + tid] = 0.f; tile[1][17 * HW + tid] = 0.f; }

    const int    ldsoff = (bx == 0) ? HW : 0;                 // skip zero row 0
    const int    count4 = (bx == 0 || bx == 6) ? 476 : 504;   // float4s staged
    const size_t srcoff = (bx == 0) ? 0 : (size_t)(h0 - 1) * HW;
    const float* xn = x + ((size_t)n * CIN + icb) * HW2 + srcoff;

    // per-thread boundary handling (branch-free, hoisted)
    const float lmask = (col0 > 0) ? 1.f : 0.f;
    const float rmask = (col0 + 7 < HW) ? 1.f : 0.f;
    const int   loff  = (col0 > 0) ? -1 : 0;
    const int   roff  = (col0 + 7 < HW) ? 7 : 0;

    float acc0[7] = {0.f, 0.f, 0.f, 0.f, 0.f, 0.f, 0.f};
    float acc1[7] = {0.f, 0.f, 0.f, 0.f, 0.f, 0.f, 0.f};

    // prologue: stage ic=0 into buf 0
    {
        float* dst = &tile[0][ldsoff];
#pragma unroll
        for (int r = 0; r < 2; ++r) {
            const int i = tid + r * 256;
            if (i < count4)
                __builtin_amdgcn_global_load_lds(
                    (const __attribute__((address_space(1))) unsigned int*)(xn + (size_t)i * 4),
                    (__attribute__((address_space(3))) unsigned int*)(dst + i * 4),
                    16, 0, 0);
        }
    }
    __syncthreads();   // drains vmcnt(0): buf0 ready for all waves

    int buf = 0;
    for (int ic = 0; ic < ICG; ++ic) {
        // issue async prefetch of ic+1 into the other buffer (flies during compute)
        if (ic + 1 < ICG) {
            const float* src = xn + (size_t)(ic + 1) * HW2;
            float* dst = &tile[buf ^ 1][ldsoff];
#pragma unroll
            for (int r = 0; r < 2; ++r) {
                const int i = tid + r * 256;
                if (i < count4)
                    __builtin_amdgcn_global_load_lds(
                        (const __attribute__((address_space(1))) unsigned int*)(src + (size_t)i * 4),
                        (__attribute__((address_space(3))) unsigned int*)(dst + i * 4),
                        16, 0, 0);
            }
        }

        // compute current channel from LDS
        const float* wa = w1 + (size_t)(icb + ic) * 9;   // oc = 0
        const float* wb = wa + (size_t)CIN * 9;          // oc = 1
        const float* tl = tile[buf];
#pragma unroll
        for (int dr = 0; dr < 3; ++dr) {
            const int base = (ty + dr) * HW + col0;
            float v[9];
            v[0] = tl[base + loff] * lmask;
#pragma unroll
            for (int k = 1; k <= 7; ++k) v[k] = tl[base + (k - 1)];
            v[8] = tl[base + roff] * rmask;
            const float a0 = wa[dr * 3 + 0], a1 = wa[dr * 3 + 1], a2 = wa[dr * 3 + 2];
            const float c0 = wb[dr * 3 + 0], c1 = wb[dr * 3 + 1], c2 = wb[dr * 3 + 2];
#pragma unroll
            for (int j = 0; j < 7; ++j) {
                acc0[j] += a0 * v[j] + a1 * v[j + 1] + a2 * v[j + 2];
                acc1[j] += c0 * v[j] + c1 * v[j + 1] + c2 * v[j + 2];
            }
        }

        __syncthreads();   // vmcnt(0): prefetch landed; all waves done reading buf
        buf ^= 1;
    }

    const size_t obase = ((size_t)kg * NIMG + n) * 2;
    float* p0 = part + (obase + 0) * HW2 + (size_t)(h0 + ty) * HW + col0;
    float* p1 = part + (obase + 1) * HW2 + (size_t)(h0 + ty) * HW + col0;
#pragma unroll
    for (int j = 0; j < 7; ++j) { p0[j] = acc0[j]; p1[j] = acc1[j]; }
}

// K1b: g = gelu(sum_kg partial + bias)
__global__ __launch_bounds__(256) void k1b_reduce_gelu(
    const float* __restrict__ part, const float* __restrict__ b1,
    float* __restrict__ g, int total4) {
    int idx = blockIdx.x * blockDim.x + threadIdx.x;
    if (idx >= total4) return;
    const size_t stride = (size_t)NIMG * 2 * HW2;  // floats per group
    const size_t e = (size_t)idx * 4;
    const int oc = (int)((e / HW2) & 1);
    float4 s = *reinterpret_cast<const float4*>(part + e);
#pragma unroll
    for (int kg = 1; kg < NKG; ++kg) {
        const float4 p = *reinterpret_cast<const float4*>(part + kg * stride + e);
        s.x += p.x; s.y += p.y; s.z += p.z; s.w += p.w;
    }
    const float bb = b1[oc];
    float4 o;
    o.x = gelu_exact(s.x + bb);
    o.y = gelu_exact(s.y + bb);
    o.z = gelu_exact(s.z + bb);
    o.w = gelu_exact(s.w + bb);
    *reinterpret_cast<float4*>(g + e) = o;
}

// ---------------------------------------------------------------------------
// Fallback monolithic K1 (used only if ws is too small for split-K buffers)
// ---------------------------------------------------------------------------
__global__ __launch_bounds__(448) void k1_conv1_gelu(
    const float* __restrict__ x, const float* __restrict__ w1,
    const float* __restrict__ b1, float* __restrict__ g) {
    const int n  = blockIdx.y;
    const int h  = blockIdx.x * 16 + threadIdx.y;
    const int w0 = threadIdx.x * 4;

    float acc0[4], acc1[4];
    const float bb0 = b1[0], bb1 = b1[1];
#pragma unroll
    for (int j = 0; j < 4; ++j) { acc0[j] = bb0; acc1[j] = bb1; }

    const float* xn = x + (size_t)n * CIN * HW2;

#pragma unroll 4
    for (int ic = 0; ic < CIN; ++ic) {
        const float* xc = xn + (size_t)ic * HW2;
        const float* wa = w1 + ic * 9;
        const float* wb = w1 + (CIN + ic) * 9;
#pragma unroll
        for (int dh = -1; dh <= 1; ++dh) {
            const int hh = h + dh;
            if (hh < 0 || hh >= HW) continue;
            const float* xr = xc + hh * HW;
            const float4 c4  = *reinterpret_cast<const float4*>(xr + w0);
            const float left  = (w0 > 0)      ? xr[w0 - 1] : 0.0f;
            const float right = (w0 + 4 < HW) ? xr[w0 + 4] : 0.0f;
            const float v0 = left, v1 = c4.x, v2 = c4.y, v3 = c4.z, v4 = c4.w, v5 = right;
            const int r = (dh + 1) * 3;
            const float a0 = wa[r], a1 = wa[r + 1], a2 = wa[r + 2];
            const float c0 = wb[r], c1 = wb[r + 1], c2 = wb[r + 2];
            acc0[0] += a0 * v0 + a1 * v1 + a2 * v2;
            acc0[1] += a0 * v1 + a1 * v2 + a2 * v3;
            acc0[2] += a0 * v2 + a1 * v3 + a2 * v4;
            acc0[3] += a0 * v3 + a1 * v4 + a2 * v5;
            acc1[0] += c0 * v0 + c1 * v1 + c2 * v2;
            acc1[1] += c0 * v1 + c1 * v2 + c2 * v3;
            acc1[2] += c0 * v2 + c1 * v3 + c2 * v4;
            acc1[3] += c0 * v3 + c1 * v4 + c2 * v5;
        }
    }

    float4 o0, o1;
    o0.x = gelu_exact(acc0[0]); o0.y = gelu_exact(acc0[1]);
    o0.z = gelu_exact(acc0[2]); o0.w = gelu_exact(acc0[3]);
    o1.x = gelu_exact(acc1[0]); o1.y = gelu_exact(acc1[1]);
    o1.z = gelu_exact(acc1[2]); o1.w = gelu_exact(acc1[3]);
    float* g0 = g + (size_t)(n * 2 + 0) * HW2 + h * HW + w0;
    float* g1 = g + (size_t)(n * 2 + 1) * HW2 + h * HW + w0;
    *reinterpret_cast<float4*>(g0) = o0;
    *reinterpret_cast<float4*>(g1) = o1;
}

// K2: s0 = softmax(gelu(conv3x3(g, w2) + b2))[ch 0]  (softmax2 == sigmoid)
__global__ __launch_bounds__(448) void k2_conv2_softmax(
    const float* __restrict__ g, const float* __restrict__ w2,
    const float* __restrict__ b2, float* __restrict__ s0) {
    const int n  = blockIdx.y;
    const int h  = blockIdx.x * 16 + threadIdx.y;
    const int w0 = threadIdx.x * 4;

    float accA[4], accB[4];
    const float bb0 = b2[0], bb1 = b2[1];
#pragma unroll
    for (int j = 0; j < 4; ++j) { accA[j] = bb0; accB[j] = bb1; }

#pragma unroll
    for (int c = 0; c < 2; ++c) {
        const float* gc = g + (size_t)(n * 2 + c) * HW2;
        const float* wa = w2 + c * 9;
        const float* wb = w2 + (2 + c) * 9;
#pragma unroll
        for (int dh = -1; dh <= 1; ++dh) {
            const int hh = h + dh;
            if (hh < 0 || hh >= HW) continue;
            const float* gr = gc + hh * HW;
            const float4 c4  = *reinterpret_cast<const float4*>(gr + w0);
            const float left  = (w0 > 0)      ? gr[w0 - 1] : 0.0f;
            const float right = (w0 + 4 < HW) ? gr[w0 + 4] : 0.0f;
            const float v0 = left, v1 = c4.x, v2 = c4.y, v3 = c4.z, v4 = c4.w, v5 = right;
            const int r = (dh + 1) * 3;
            const float a0 = wa[r], a1 = wa[r + 1], a2 = wa[r + 2];
            const float c0 = wb[r], c1 = wb[r + 1], c2 = wb[r + 2];
            accA[0] += a0 * v0 + a1 * v1 + a2 * v2;
            accA[1] += a0 * v1 + a1 * v2 + a2 * v3;
            accA[2] += a0 * v2 + a1 * v3 + a2 * v4;
            accA[3] += a0 * v3 + a1 * v4 + a2 * v5;
            accB[0] += c0 * v0 + c1 * v1 + c2 * v2;
            accB[1] += c0 * v1 + c1 * v2 + c2 * v3;
            accB[2] += c0 * v2 + c1 * v3 + c2 * v4;
            accB[3] += c0 * v3 + c1 * v4 + c2 * v5;
        }
    }

    float4 o;
    o.x = 1.0f / (1.0f + expf(gelu_exact(accB[0]) - gelu_exact(accA[0])));
    o.y = 1.0f / (1.0f + expf(gelu_exact(accB[1]) - gelu_exact(accA[1])));
    o.z = 1.0f / (1.0f + expf(gelu_exact(accB[2]) - gelu_exact(accA[2])));
    o.w = 1.0f / (1.0f + expf(gelu_exact(accB[3]) - gelu_exact(accA[3])));
    *reinterpret_cast<float4*>(s0 + (size_t)n * HW2 + h * HW + w0) = o;
}

// K3: out[b][c][t][h][w] = s0*x1 + (1-s0)*x2
__global__ __launch_bounds__(256) void k3_blend(
    const float* __restrict__ x, const float* __restrict__ s0,
    float* __restrict__ out, int total4) {
    int idx = blockIdx.x * blockDim.x + threadIdx.x;
    if (idx >= total4) return;
    const int W4 = HW / 4;
    int w4  = idx % W4;
    int tmp = idx / W4;
    int h   = tmp % HW; tmp /= HW;
    int t   = tmp % 16; tmp /= 16;
    int c   = tmp % 64;
    int b   = tmp / 64;
    const int n = b * 16 + t;

    const size_t px = (size_t)h * HW + w4 * 4;
    const float4 x1 = *reinterpret_cast<const float4*>(x + (size_t)(n * CIN + c)      * HW2 + px);
    const float4 x2 = *reinterpret_cast<const float4*>(x + (size_t)(n * CIN + c + 64) * HW2 + px);
    const float4 s  = *reinterpret_cast<const float4*>(s0 + (size_t)n * HW2 + px);

    float4 o;
    o.x = s.x * x1.x + (1.0f - s.x) * x2.x;
    o.y = s.y * x1.y + (1.0f - s.y) * x2.y;
    o.z = s.z * x1.z + (1.0f - s.z) * x2.z;
    o.w = s.w * x1.w + (1.0f - s.w) * x2.w;
    *reinterpret_cast<float4*>(out + (size_t)idx * 4) = o;
}

extern "C" void kernel_launch(void* const* d_in, const int* in_sizes, int n_in,
                              void* d_out, int out_size, void* d_ws, size_t ws_size,
                              hipStream_t stream) {
    const float* x  = (const float*)d_in[0];
    const float* w1 = (const float*)d_in[1];
    const float* b1 = (const float*)d_in[2];
    const float* w2 = (const float*)d_in[3];
    const float* b2 = (const float*)d_in[4];
    float* out = (float*)d_out;

    const size_t partF = (size_t)NKG * NIMG * 2 * HW2;  // 25.7 MB
    const size_t gF    = (size_t)NIMG * 2 * HW2;        //  6.4 MB
    const size_t s0F   = (size_t)NIMG * HW2;            //  3.2 MB
    const size_t need  = (partF + gF + s0F) * sizeof(float);

    dim3 grd(7, NIMG);

    float *g, *s0;
    if (ws_size >= need) {
        float* part = (float*)d_ws;
        g  = part + partF;
        s0 = g + gF;
        dim3 grdp(7, NIMG, NKG);
        k1_partial<<<grdp, 256, 0, stream>>>(x, w1, part);
        const int total4g = (int)(gF / 4);
        k1b_reduce_gelu<<<(total4g + 255) / 256, 256, 0, stream>>>(part, b1, g, total4g);
    } else {
        g  = (float*)d_ws;
        s0 = g + gF;
        dim3 blk(28, 16);
        k1_conv1_gelu<<<grd, blk, 0, stream>>>(x, w1, b1, g);
    }

    dim3 blk2(28, 16);
    k2_conv2_softmax<<<grd, blk2, 0, stream>>>(g, w2, b2, s0);

    const int total4 = 4 * 64 * 16 * HW * (HW / 4);
    k3_blend<<<(total4 + 255) / 256, 256, 0, stream>>>(x, s0, out, total4);
}